// Round 10
// baseline (159.987 us; speedup 1.0000x reference)
//
#include <hip/hip_runtime.h>
#include <hip/hip_bf16.h>

using u16 = unsigned short;
using u32 = unsigned int;

typedef __bf16 bf16x8 __attribute__((ext_vector_type(8)));
typedef float f32x4 __attribute__((ext_vector_type(4)));

__device__ __forceinline__ u16 f2bf(float f) {
  union { float f; u32 u; } c; c.f = f;
  u32 u = c.u;
  u32 r = u + 0x7fffu + ((u >> 16) & 1u);   // RNE
  return (u16)(r >> 16);
}
__device__ __forceinline__ u32 pack2(float a, float b) {
  return (u32)f2bf(a) | ((u32)f2bf(b) << 16);
}

constexpr int Bb  = 64;    // graphs
constexpr int L   = 1024;  // nodes/graph
constexpr int IN  = 128;
constexpr int OUT = 128;
constexpr int FLR = 64;
constexpr int N   = Bb * L;

// ---------------------------------------------------------------------------
// k_sh — ROUND 10: k_pack folded in (one fewer dispatch; the 2.5 µs Wout/Wh
// pack no longer sits serially ahead of k_sh).
//   blocks 0..1023: R0-verified body — x A-frags + s fp32 partials; Wh
//     B-frags built ON THE FLY from global Wh (32 KB, L1/L2-hot; measured
//     neutral vs pre-packed in R1/R2). Plus R9's additions: xbf A-frag dump
//     and sqb = |s|^2 store.
//   block 1024: Wout -> Bp MFMA B-frag pack (R0's verified loop).
// k_fused is BYTE-IDENTICAL to round 9 (passing, 65.4 µs).
// ---------------------------------------------------------------------------
__global__ __launch_bounds__(256) void k_sh(
    const float* __restrict__ x, const float* __restrict__ Ws, const float* __restrict__ bs,
    const float* __restrict__ Wh, const float* __restrict__ bh,
    const float* __restrict__ Wout,
    float* __restrict__ s_buf, u16* __restrict__ h_buf, u16* __restrict__ xbf,
    float* __restrict__ sqb, u16* __restrict__ Bp)
{
  const int blk = blockIdx.x;
  if (blk >= N / 64) {
    // ---- W_out pack for k_fused's GEMM (4096 frag-slots, 8 loads each)
#pragma unroll
    for (int it = 0; it < 16; ++it) {
      int t2 = it * 256 + threadIdx.x;     // 4096 frag-lanes
      int lane = t2 & 63, kstep = (t2 >> 6) & 7, ntile = t2 >> 9;
      int n  = ntile * 16 + (lane & 15);
      int kb = kstep * 32 + (lane >> 4) * 8;
      u16* dst = Bp + (size_t)t2 * 8;
#pragma unroll
      for (int j = 0; j < 8; ++j) dst[j] = f2bf(Wout[(kb + j) * OUT + n]);
    }
    return;
  }

  const int tid = threadIdx.x;
  const int lane = tid & 63;
  const int w = __builtin_amdgcn_readfirstlane(tid >> 6);
  const int mb = blk * 64 + w * 16;        // m-tile base node
  const int col = lane & 15;
  const int kq  = lane >> 4;               // 0..3
  const int mrow = mb + col;               // this lane's A row

  const float* xr = x + (size_t)mrow * IN;

  // ---- load x A-frags (fp32->bf16) + accumulate s partials in fp32
  float sp0 = 0.f, sp1 = 0.f, sp2 = 0.f, sp3 = 0.f;
  bf16x8 a[4];
#pragma unroll
  for (int ks = 0; ks < 4; ++ks) {
    float4 xa = *(const float4*)(xr + ks * 32 + kq * 8);
    float4 xb = *(const float4*)(xr + ks * 32 + kq * 8 + 4);
    float xf[8] = {xa.x, xa.y, xa.z, xa.w, xb.x, xb.y, xb.z, xb.w};
#pragma unroll
    for (int j = 0; j < 8; ++j) {
      const float4 wsr = *(const float4*)(Ws + (size_t)(ks * 32 + kq * 8 + j) * 4);
      sp0 = fmaf(xf[j], wsr.x, sp0);
      sp1 = fmaf(xf[j], wsr.y, sp1);
      sp2 = fmaf(xf[j], wsr.z, sp2);
      sp3 = fmaf(xf[j], wsr.w, sp3);
    }
    union { __hip_bfloat162 h2[4]; bf16x8 v; } cv;
    cv.h2[0] = __float22bfloat162_rn(float2{xf[0], xf[1]});
    cv.h2[1] = __float22bfloat162_rn(float2{xf[2], xf[3]});
    cv.h2[2] = __float22bfloat162_rn(float2{xf[4], xf[5]});
    cv.h2[3] = __float22bfloat162_rn(float2{xf[6], xf[7]});
    a[ks] = cv.v;
  }

  // ---- dump A-frags for k_fused's GEMM (frag slot = (tile*4+ks)*64+lane)
  if (xbf) {
#pragma unroll
    for (int ks = 0; ks < 4; ++ks)
      *(bf16x8*)(xbf + (((size_t)(blk * 4 + w) * 4 + ks) * 64 + lane) * 8) = a[ks];
  }

  // ---- h GEMM: 4 n-tiles x 4 k-steps; B-frag from Wh on the fly (R0 body)
  f32x4 acc[4];
#pragma unroll
  for (int nt = 0; nt < 4; ++nt) acc[nt] = f32x4{0.f, 0.f, 0.f, 0.f};

#pragma unroll
  for (int nt = 0; nt < 4; ++nt) {
#pragma unroll
    for (int ks = 0; ks < 4; ++ks) {
      const float* whb = Wh + (size_t)(ks * 32 + kq * 8) * FLR + nt * 16 + col;
      union { __hip_bfloat162 h2[4]; bf16x8 v; } bv;
#pragma unroll
      for (int j = 0; j < 4; ++j)
        bv.h2[j] = __float22bfloat162_rn(float2{whb[(2 * j) * FLR], whb[(2 * j + 1) * FLR]});
      acc[nt] = __builtin_amdgcn_mfma_f32_16x16x32_bf16(a[ks], bv.v, acc[nt], 0, 0, 0);
    }
  }

  // ---- s reduce + store (fp32) + |s|^2 for the expansion-form distance
  sp0 += __shfl_xor(sp0, 16, 64); sp0 += __shfl_xor(sp0, 32, 64);
  sp1 += __shfl_xor(sp1, 16, 64); sp1 += __shfl_xor(sp1, 32, 64);
  sp2 += __shfl_xor(sp2, 16, 64); sp2 += __shfl_xor(sp2, 32, 64);
  sp3 += __shfl_xor(sp3, 16, 64); sp3 += __shfl_xor(sp3, 32, 64);
  if (kq == 0) {
    float4 sv;
    sv.x = sp0 + bs[0]; sv.y = sp1 + bs[1];
    sv.z = sp2 + bs[2]; sv.w = sp3 + bs[3];
    *(float4*)(s_buf + (size_t)mrow * 4) = sv;
    sqb[mrow] = fmaf(sv.w, sv.w, fmaf(sv.z, sv.z, fmaf(sv.y, sv.y, sv.x * sv.x)));
  }

  // ---- h epilogue: bias + bf16 store (C-layout: col=lane&15, row=kq*4+r)
#pragma unroll
  for (int nt = 0; nt < 4; ++nt) {
    float bias = bh[nt * 16 + col];
#pragma unroll
    for (int r = 0; r < 4; ++r) {
      float v = acc[nt][r] + bias;
      h_buf[(size_t)(mb + kq * 4 + r) * FLR + nt * 16 + col] = f2bf(v);
    }
  }
}

// ---------------------------------------------------------------------------
// k_fused — BYTE-IDENTICAL to round 9 (passing, 65.4 µs): norm-expansion
// distances + fmed3 ladder + 3-level merge + precomputed wk + shuffle-free
// aggregation + MFMA output GEMM with pre-packed A (xbf) and B (Bp) frags.
// ---------------------------------------------------------------------------
__global__ __launch_bounds__(512) void k_fused(
    const float* __restrict__ s_buf, const u16* __restrict__ h_buf,
    const float* __restrict__ x, const u16* __restrict__ Bp,
    const u16* __restrict__ xbf, const float* __restrict__ sqb,
    const float* __restrict__ bout, float* __restrict__ out)
{
  __shared__ alignas(16) float lists[8 * 64 * 17];   // 8704 floats (34816 B)
  __shared__ float fk[64 * 17];                      // final 16 keys per node
  u16* agg_lds = (u16*)lists;          // [64][136] bf16, bytes [0, 17408)
  float* wk = lists + 4608;            // [64*17] f32 weights (dead region at write)

  const int lane = threadIdx.x & 63;
  const int w = __builtin_amdgcn_readfirstlane(threadIdx.x >> 6);
  const int g = blockIdx.y;
  const int nb0 = blockIdx.x * 64;
  const int node = g * L + nb0 + lane;

  const float4 si = *(const float4*)(s_buf + (size_t)node * 4);
  const float4* __restrict__ sg = (const float4*)(s_buf + (size_t)g * L * 4);
  const float*  __restrict__ sqg = sqb + (size_t)g * L;
  const int jb = __builtin_amdgcn_readfirstlane(w * 128);

  const float m2x = -2.0f * si.x, m2y = -2.0f * si.y;
  const float m2z = -2.0f * si.z, m2w = -2.0f * si.w;
  const float sqi = fmaf(si.w, si.w, fmaf(si.z, si.z, fmaf(si.y, si.y, si.x * si.x)));

  float b[16];
#pragma unroll
  for (int k = 0; k < 16; ++k) b[k] = 3.0e38f;

#pragma unroll 4
  for (int j = 0; j < 128; ++j) {
    float4 sj = sg[jb + j];
    float base = sqi + sqg[jb + j];
    float d2 = fmaf(m2w, sj.w, fmaf(m2z, sj.z, fmaf(m2y, sj.y, fmaf(m2x, sj.x, base))));
    u32 db = __float_as_uint(d2);
    float key = __uint_as_float((db & 0xFFFFFC00u) | (u32)(jb + j));
#pragma unroll
    for (int k = 15; k >= 1; --k) b[k] = __builtin_amdgcn_fmed3f(key, b[k - 1], b[k]);
    b[0] = fminf(key, b[0]);
  }

#pragma unroll
  for (int k = 0; k < 16; ++k) lists[(w * 64 + lane) * 17 + k] = b[k];
  __syncthreads();

  float c[16];
  if (w < 4) {
#pragma unroll
    for (int i = 0; i < 16; ++i)
      c[i] = fminf(b[i], lists[((w + 4) * 64 + lane) * 17 + (15 - i)]);
#pragma unroll
    for (int dd = 8; dd >= 1; dd >>= 1) {
#pragma unroll
      for (int i = 0; i < 16; ++i) {
        if ((i & dd) == 0) {
          float lo = fminf(c[i], c[i | dd]);
          float hi = fmaxf(c[i], c[i | dd]);
          c[i] = lo; c[i | dd] = hi;
        }
      }
    }
#pragma unroll
    for (int k = 0; k < 16; ++k) lists[(w * 64 + lane) * 17 + k] = c[k];
  }
  __syncthreads();
  if (w < 2) {
#pragma unroll
    for (int i = 0; i < 16; ++i)
      c[i] = fminf(c[i], lists[((w + 2) * 64 + lane) * 17 + (15 - i)]);
#pragma unroll
    for (int dd = 8; dd >= 1; dd >>= 1) {
#pragma unroll
      for (int i = 0; i < 16; ++i) {
        if ((i & dd) == 0) {
          float lo = fminf(c[i], c[i | dd]);
          float hi = fmaxf(c[i], c[i | dd]);
          c[i] = lo; c[i | dd] = hi;
        }
      }
    }
#pragma unroll
    for (int k = 0; k < 16; ++k) lists[(w * 64 + lane) * 17 + k] = c[k];
  }
  __syncthreads();
  if (w == 0) {
#pragma unroll
    for (int i = 0; i < 16; ++i) {
      float o = lists[(64 + lane) * 17 + (15 - i)];
      float kf = fminf(c[i], o);
      fk[lane * 17 + i] = kf;
      wk[lane * 17 + i] =
          __expf(-10.0f * __uint_as_float(__float_as_uint(kf) & 0xFFFFFC00u));
    }
  }
  __syncthreads();        // fk/wk ready; lists[] selection data dead

  // ---- aggregation: lane <-> (node, 8-dim chunk); no shuffles
  {
    const int q     = lane & 7;              // dim chunk (8 bf16 = 16 B)
    const int nodeA = w * 8 + (lane >> 3);   // 0..63
    const u16* __restrict__ hg = h_buf + (size_t)g * L * FLR;

    float m[8], xx[8];
#pragma unroll
    for (int j = 0; j < 8; ++j) { m[j] = 0.f; xx[j] = -3.0e38f; }

#pragma unroll 4
    for (int k = 0; k < 16; ++k) {
      u32 u    = __float_as_uint(fk[nodeA * 17 + k]);
      float wg = wk[nodeA * 17 + k];
      const uint4 hv = ((const uint4*)(hg + (size_t)(u & 1023u) * FLR))[q];
      u32 p[4] = {hv.x, hv.y, hv.z, hv.w};
#pragma unroll
      for (int d = 0; d < 4; ++d) {
        float lo = __uint_as_float(p[d] << 16) * wg;
        float hi = __uint_as_float(p[d] & 0xFFFF0000u) * wg;
        m[2 * d]     += lo;  xx[2 * d]     = fmaxf(xx[2 * d], lo);
        m[2 * d + 1] += hi;  xx[2 * d + 1] = fmaxf(xx[2 * d + 1], hi);
      }
    }

    uint4 om, ox;
    om.x = pack2(m[0] * 0.0625f, m[1] * 0.0625f);
    om.y = pack2(m[2] * 0.0625f, m[3] * 0.0625f);
    om.z = pack2(m[4] * 0.0625f, m[5] * 0.0625f);
    om.w = pack2(m[6] * 0.0625f, m[7] * 0.0625f);
    ox.x = pack2(xx[0], xx[1]); ox.y = pack2(xx[2], xx[3]);
    ox.z = pack2(xx[4], xx[5]); ox.w = pack2(xx[6], xx[7]);
    *(uint4*)(&agg_lds[nodeA * 136 + q * 8])       = om;
    *(uint4*)(&agg_lds[nodeA * 136 + FLR + q * 8]) = ox;
  }
  __syncthreads();

  // ---- output GEMM
  const int mt  = w & 3;
  const int ntb = (w >> 2) * 4;
  const int rowL = mt * 16 + (lane & 15);
  const int grow = g * L + nb0 + rowL;
  const int kq8 = (lane >> 4) * 8;

  f32x4 acc[4];
#pragma unroll
  for (int nt = 0; nt < 4; ++nt) acc[nt] = f32x4{0.f, 0.f, 0.f, 0.f};

  const float* xr = x + (size_t)grow * IN;
  const bf16x8* __restrict__ bp = (const bf16x8*)Bp;
  const int tileA = (g * 16 + blockIdx.x) * 4 + mt;

#pragma unroll
  for (int ks = 0; ks < 8; ++ks) {
    bf16x8 a;
    if (ks < 4) {
      if (xbf) {
        a = *(const bf16x8*)(xbf + (((size_t)tileA * 4 + ks) * 64 + lane) * 8);
      } else {
        float4 xa = *(const float4*)(xr + ks * 32 + kq8);
        float4 xb = *(const float4*)(xr + ks * 32 + kq8 + 4);
        union { __hip_bfloat162 h2[4]; bf16x8 v; } cv;
        cv.h2[0] = __float22bfloat162_rn(float2{xa.x, xa.y});
        cv.h2[1] = __float22bfloat162_rn(float2{xa.z, xa.w});
        cv.h2[2] = __float22bfloat162_rn(float2{xb.x, xb.y});
        cv.h2[3] = __float22bfloat162_rn(float2{xb.z, xb.w});
        a = cv.v;
      }
    } else {
      a = *(const bf16x8*)(&agg_lds[rowL * 136 + (ks - 4) * 32 + kq8]);
    }
#pragma unroll
    for (int nt = 0; nt < 4; ++nt) {
      bf16x8 bb = bp[((ntb + nt) * 8 + ks) * 64 + lane];
      acc[nt] = __builtin_amdgcn_mfma_f32_16x16x32_bf16(a, bb, acc[nt], 0, 0, 0);
    }
  }

  const int rbase = (lane >> 4) * 4;
  const int colO = lane & 15;
  const int mrow = g * L + nb0 + mt * 16;
#pragma unroll
  for (int nt = 0; nt < 4; ++nt) {
    float bias = bout[(ntb + nt) * 16 + colO];
#pragma unroll
    for (int r = 0; r < 4; ++r) {
      float v = acc[nt][r] + bias;
      out[(size_t)(mrow + rbase + r) * OUT + (ntb + nt) * 16 + colO] = fmaxf(v, 0.0f);
    }
  }
}

extern "C" void kernel_launch(void* const* d_in, const int* in_sizes, int n_in,
                              void* d_out, int out_size, void* d_ws, size_t ws_size,
                              hipStream_t stream) {
  const float* x    = (const float*)d_in[0];
  const float* Ws   = (const float*)d_in[1];
  const float* bs   = (const float*)d_in[2];
  const float* Wh   = (const float*)d_in[3];
  const float* bh   = (const float*)d_in[4];
  const float* Wout = (const float*)d_in[5];
  const float* bout = (const float*)d_in[6];
  float* out = (float*)d_out;

  char* ws = (char*)d_ws;
  float* s_buf = (float*)ws;                                      // 1 MiB
  u16*   h_buf = (u16*)(ws + (1 << 20));                          // 8 MiB
  u16*   Bp    = (u16*)(ws + (1 << 20) + (8 << 20));              // 64 KiB
  float* sqb   = (float*)(ws + (1 << 20) + (8 << 20) + (80 << 10)); // 256 KiB
  u16*   xbf   = (ws_size >= (26u << 20)) ? (u16*)(ws + (10 << 20)) : nullptr;

  k_sh<<<N / 64 + 1, 256, 0, stream>>>(x, Ws, bs, Wh, bh, Wout,
                                       s_buf, h_buf, xbf, sqb, Bp);
  dim3 gknn(L / 64, Bb);
  k_fused<<<gknn, 512, 0, stream>>>(s_buf, h_buf, x, Bp, xbf, sqb, bout, out);
}